// Round 4
// baseline (527.948 us; speedup 1.0000x reference)
//
#include <hip/hip_runtime.h>
#include <math.h>

typedef unsigned short u16;
typedef __attribute__((ext_vector_type(8))) short s8v;   // 8 x bf16 (4 VGPRs)
typedef __attribute__((ext_vector_type(4))) float f4v;   // MFMA accumulator

#define NUM_CLASSES 91
#define NUM_ANCHORS 9
#define NT 130             // total 16x8 spatial tiles across 5 levels
#define TW_STRIDE (256*256*9)

struct Tab {
    int tstart[5];  // first tile index per level
    int tw[5];      // tiles along W
    int H[5], W[5], GP0[5];
};

__device__ __forceinline__ u16 f2bf(float f) {
    unsigned u = __float_as_uint(f);
    u += 0x7fffu + ((u >> 16) & 1u);
    return (u16)(u >> 16);
}

// ---------------------------------------------------------------------------
// fp32 NCHW -> bf16 [pixel][256] (channel-last), per level
// ---------------------------------------------------------------------------
__global__ __launch_bounds__(256) void conv2bf(const float* __restrict__ x,
                                               u16* __restrict__ out,
                                               int HW, int gp0)
{
    int p = blockIdx.x * 64 + (threadIdx.x & 63);
    int cg = threadIdx.x >> 6;              // 0..3
    if (p >= HW) return;
    #pragma unroll
    for (int pass = 0; pass < 8; ++pass) {
        int c0 = pass * 32 + cg * 8;
        s8v v8;
        #pragma unroll
        for (int j = 0; j < 8; ++j)
            v8[j] = (short)f2bf(x[(c0 + j) * HW + p]);
        *(s8v*)(out + (((gp0 + p) << 8) + c0)) = v8;
    }
}

// ---------------------------------------------------------------------------
// Pack conv weights [C_out][256][3][3] fp32 -> bf16 MFMA B-fragment order
// ---------------------------------------------------------------------------
__global__ __launch_bounds__(256) void pack_w(const float* __restrict__ w,
                                              u16* __restrict__ dst,
                                              int c_out_real, int nco16)
{
    int idx = blockIdx.x * 256 + threadIdx.x;
    int total = 72 * nco16 * 64;
    if (idx >= total) return;
    int lane = idx & 63;
    int t2 = idx >> 6;
    int co16 = t2 % nco16;
    int chunk = t2 / nco16;
    int tap = chunk >> 3, cib = chunk & 7;
    int co = co16 * 16 + (lane & 15);
    int ci0 = cib * 32 + ((lane >> 4) << 3);
    s8v v8;
    #pragma unroll
    for (int j = 0; j < 8; ++j) {
        float v = (co < c_out_real) ? w[((co << 8) + ci0 + j) * 9 + tap] : 0.f;
        v8[j] = (short)f2bf(v);
    }
    *(s8v*)(dst + (size_t)idx * 8) = v8;
}

// ---------------------------------------------------------------------------
// LDS-staged implicit-GEMM conv, 2-phase pipelined (double-buffered LDS,
// async stage split, tap-0 B prefetch). Block: 256 thr = 4 waves
// (2 px-halves x 2 co-groups). Spatial tile 16w x 8h; halo 18x10.
// MODE: 0 = tower (relu, bf16 ch-last store, dual-head via blockIdx.z)
//       1 = cls out (sigmoid + scatter to d_out)
//       2 = reg out (raw fp32 [pixel][48])
// ---------------------------------------------------------------------------
#define DO_TAPS(T0, T1)                                                       \
    _Pragma("unroll")                                                         \
    for (int tap = (T0); tap < (T1); ++tap) {                                 \
        s8v b[4];                                                             \
        _Pragma("unroll")                                                     \
        for (int n = 0; n < 4; ++n)                                           \
            b[n] = *(const s8v*)(bb +                                         \
                (((size_t)((tap * 8 + cib) * nco16 + c16n[n])) << 9));        \
        const int tofs = ((tap / 3) * 18 + (tap % 3)) * 40;                   \
        s8v a[4];                                                             \
        _Pragma("unroll")                                                     \
        for (int s = 0; s < 4; ++s)                                           \
            a[s] = *(const s8v*)(&L[rowbase[s] + tofs]);                      \
        _Pragma("unroll")                                                     \
        for (int s = 0; s < 4; ++s)                                           \
            _Pragma("unroll")                                                 \
            for (int n = 0; n < 4; ++n)                                       \
                acc[s][n] = __builtin_amdgcn_mfma_f32_16x16x32_bf16(          \
                    a[s], b[n], acc[s][n], 0, 0, 0);                          \
    }

template<int MODE>
__global__ __launch_bounds__(256, 2) void conv_lds(
    const u16* __restrict__ actC, u16* __restrict__ outC,
    const u16* __restrict__ actR, u16* __restrict__ outR,
    const u16* __restrict__ wC, const u16* __restrict__ wR,
    const float* __restrict__ bC, const float* __restrict__ bR,
    float* __restrict__ fout, int nco16, Tab tab)
{
    __shared__ u16 lds[2][7200];   // 2 x 14.4 KB: [halo px][40 u16]

    const int bx = blockIdx.x;
    int lvl = 0;
    if (bx >= tab.tstart[1]) lvl = 1;
    if (bx >= tab.tstart[2]) lvl = 2;
    if (bx >= tab.tstart[3]) lvl = 3;
    if (bx >= tab.tstart[4]) lvl = 4;
    const int H = tab.H[lvl], W = tab.W[lvl], gp0 = tab.GP0[lvl];
    const int t = bx - tab.tstart[lvl];
    const int tw = tab.tw[lvl];
    const int w0 = (t % tw) * 16;
    const int h0 = (t / tw) * 8;

    const int head = (MODE == 0) ? blockIdx.z : 0;
    const u16* act = head ? actR : actC;
    const u16* wpk = head ? wR : wC;
    const float* bias = head ? bR : bC;

    const int tid = threadIdx.x;
    const int lane = tid & 63, wv = tid >> 6;
    const int wv1 = wv & 1;                       // h-half: rows 0-3 / 4-7
    const int co16b = blockIdx.y * 8 + (wv >> 1) * 4;
    const int kgrp8 = (lane >> 4) << 3;           // ci sub-offset (u16)

    // precompute staging slots (720 16B-lane-loads, <=3 per thread)
    int sofs[3], slds[3];
    bool svalid[3], slive[3];
    #pragma unroll
    for (int i = 0; i < 3; ++i) {
        int k = tid + i * 256;
        slive[i] = k < 720;
        int kk = slive[i] ? k : 0;
        int px = kk >> 2, part = kk & 3;
        int hh = px / 18, ww = px % 18;
        int gh = h0 + hh - 1, gw = w0 + ww - 1;
        svalid[i] = ((unsigned)gh < (unsigned)H) && ((unsigned)gw < (unsigned)W);
        sofs[i] = ((gp0 + gh * W + gw) << 8) + part * 8;
        slds[i] = px * 40 + part * 8;
    }

    // per-wave constants
    int c16n[4];
    #pragma unroll
    for (int n = 0; n < 4; ++n) {
        int c = co16b + n;
        c16n[n] = (c >= nco16) ? nco16 - 1 : c;
    }
    const u16* bb = wpk + (lane << 3);
    int rowbase[4];
    #pragma unroll
    for (int s = 0; s < 4; ++s)
        rowbase[s] = ((wv1 * 4 + s) * 18 + (lane & 15)) * 40 + kgrp8;

    f4v acc[4][4];
    #pragma unroll
    for (int s = 0; s < 4; ++s)
        #pragma unroll
        for (int n = 0; n < 4; ++n)
            acc[s][n] = (f4v){0.f, 0.f, 0.f, 0.f};

    s8v pre[3];     // in-flight stage loads
    s8v b0[4];      // tap-0 B prefetch

    auto ISSUE_S = [&](int cc) {
        #pragma unroll
        for (int i = 0; i < 3; ++i) {
            s8v v = {};
            if (slive[i] && svalid[i])
                v = *(const s8v*)(act + sofs[i] + cc * 32);
            pre[i] = v;
        }
    };
    auto ISSUE_B0 = [&](int cc) {
        #pragma unroll
        for (int n = 0; n < 4; ++n)
            b0[n] = *(const s8v*)(bb + (((size_t)(cc * nco16 + c16n[n])) << 9));
    };

    ISSUE_S(0);
    ISSUE_B0(0);
    int cur = 0;
    for (int cib = 0; cib < 8; ++cib) {
        // drain stage loads, write LDS buffer `cur`
        #pragma unroll
        for (int i = 0; i < 3; ++i)
            if (slive[i]) *(s8v*)(&lds[cur][slds[i]]) = pre[i];
        __syncthreads();
        const u16* L = lds[cur];

        // tap 0 (B prefetched across the barrier)
        {
            s8v a[4];
            #pragma unroll
            for (int s = 0; s < 4; ++s)
                a[s] = *(const s8v*)(&L[rowbase[s]]);
            #pragma unroll
            for (int s = 0; s < 4; ++s)
                #pragma unroll
                for (int n = 0; n < 4; ++n)
                    acc[s][n] = __builtin_amdgcn_mfma_f32_16x16x32_bf16(
                        a[s], b0[n], acc[s][n], 0, 0, 0);
        }
        DO_TAPS(1, 3)
        if (cib < 7) ISSUE_S(cib + 1);      // stage t+1 hides under taps 3..8
        DO_TAPS(3, 8)
        if (cib < 7) ISSUE_B0(cib + 1);     // next tap-0 B crosses the barrier
        DO_TAPS(8, 9)
        cur ^= 1;
    }

    // ---- epilogue ----
    u16* outw = head ? outR : outC;
    #pragma unroll
    for (int n = 0; n < 4; ++n) {
        const int co = (co16b + n) * 16 + (lane & 15);
        #pragma unroll
        for (int s = 0; s < 4; ++s) {
            const int h = h0 + wv1 * 4 + s;
            #pragma unroll
            for (int j = 0; j < 4; ++j) {
                const int w = w0 + ((lane >> 4) << 2) + j;
                if (h < H && w < W) {
                    const int p = h * W + w;
                    if (MODE == 0) {
                        float v = acc[s][n][j] + bias[co];
                        outw[((gp0 + p) << 8) + co] = f2bf(fmaxf(v, 0.f));
                    } else if (MODE == 1) {
                        if (co < NUM_ANCHORS * NUM_CLASSES) {
                            float v = acc[s][n][j] + bias[co];
                            int a = co / NUM_CLASSES;
                            int k = co - a * NUM_CLASSES;
                            float sg = 1.f / (1.f + __expf(-v));
                            fout[((size_t)(gp0 + p) * 9 + a) * 95 + k] = sg;
                        }
                    } else {
                        if (co < 36)
                            fout[(gp0 + p) * 48 + co] = acc[s][n][j] + bias[co];
                    }
                }
            }
        }
    }
}

// ---------------------------------------------------------------------------
// box decode from raw [pixel][48]
// ---------------------------------------------------------------------------
__global__ __launch_bounds__(256) void decode_boxes(
    const float* __restrict__ raw, float* __restrict__ out, Tab tab)
{
    int idx = blockIdx.x * 256 + threadIdx.x;
    if (idx >= 13343 * 9) return;
    int gp = idx / 9, a = idx % 9;
    int lvl = 0;
    if (gp >= tab.GP0[1]) lvl = 1;
    if (gp >= tab.GP0[2]) lvl = 2;
    if (gp >= tab.GP0[3]) lvl = 3;
    if (gp >= tab.GP0[4]) lvl = 4;
    int p = gp - tab.GP0[lvl];
    int W = tab.W[lvl];
    int h = p / W, wc = p % W;
    float stride = (float)(8 << lvl);
    float base = (float)(32 << lvl);

    float dx = raw[gp * 48 + a * 4 + 0];
    float dy = raw[gp * 48 + a * 4 + 1];
    float dw = raw[gp * 48 + a * 4 + 2];
    float dh = raw[gp * 48 + a * 4 + 3];

    const float scales[3] = {1.f, 1.2599210498948732f, 1.5874010519681994f};
    const float hr[3] = {0.70710678118654752f, 1.f, 1.41421356237309505f};
    int ri = a / 3, si = a % 3;
    float sz = base * scales[si];
    float ah = hr[ri] * sz;
    float aw = sz / hr[ri];
    float acx = (float)wc * stride;
    float acy = (float)h * stride;

    const float CLAMP = 4.135166556742356f;
    dw = fminf(dw, CLAMP);
    dh = fminf(dh, CLAMP);
    float pcx = dx * aw + acx;
    float pcy = dy * ah + acy;
    float pw = expf(dw) * aw;
    float ph = expf(dh) * ah;

    float* o = out + ((size_t)gp * 9 + a) * 95 + 91;
    o[0] = pcx - 0.5f * pw;
    o[1] = pcy - 0.5f * ph;
    o[2] = pcx + 0.5f * pw;
    o[3] = pcy + 0.5f * ph;
}

// ---------------------------------------------------------------------------
extern "C" void kernel_launch(void* const* d_in, const int* in_sizes, int n_in,
                              void* d_out, int out_size, void* d_ws, size_t ws_size,
                              hipStream_t stream)
{
    const float* feats[5];
    for (int i = 0; i < 5; ++i) feats[i] = (const float*)d_in[i];
    const float* cls_tw = (const float*)d_in[5];
    const float* cls_tb = (const float*)d_in[6];
    const float* cls_ow = (const float*)d_in[7];
    const float* cls_ob = (const float*)d_in[8];
    const float* reg_tw = (const float*)d_in[9];
    const float* reg_tb = (const float*)d_in[10];
    const float* reg_ow = (const float*)d_in[11];
    const float* reg_ob = (const float*)d_in[12];
    float* out = (float*)d_out;

    static const Tab TAB = {
        {0, 91, 119, 127, 129},
        {7, 4, 2, 1, 1},
        {100, 50, 25, 13, 7},
        {100, 50, 25, 13, 7},
        {0, 10000, 12500, 13125, 13294}
    };
    static const int HWs[5] = {10000, 2500, 625, 169, 49};

    char* wsb = (char*)d_ws;
    const size_t AS = 6832128;                 // act buffer stride (bytes)
    u16* A = (u16*)(wsb + 0 * AS);
    u16* B = (u16*)(wsb + 1 * AS);
    u16* C = (u16*)(wsb + 2 * AS);
    u16* D = (u16*)(wsb + 3 * AS);
    u16* PC = (u16*)(wsb + 4 * AS);            // packed cls weights (<=3.84MB)
    u16* PR = (u16*)(wsb + 4 * AS + 3833856);  // packed reg weights (<=1.18MB)
    float* RAW = (float*)B;                    // reg raw out, reuses B

    // 1) feats -> bf16 channel-last into A
    for (int l = 0; l < 5; ++l)
        conv2bf<<<(HWs[l] + 63) / 64, 256, 0, stream>>>(feats[l], A, HWs[l], TAB.GP0[l]);

    // 2) tower stages, both heads fused
    const u16* cin[4]   = {A, B, D, B};
    u16*       cout_[4] = {B, D, B, D};
    const u16* rin[4]   = {A, C, A, C};
    u16*       rout[4]  = {C, A, C, A};

    for (int s = 0; s < 4; ++s) {
        pack_w<<<(72 * 16 * 64 + 255) / 256, 256, 0, stream>>>(cls_tw + s * TW_STRIDE, PC, 256, 16);
        pack_w<<<(72 * 16 * 64 + 255) / 256, 256, 0, stream>>>(reg_tw + s * TW_STRIDE, PR, 256, 16);
        conv_lds<0><<<dim3(NT, 2, 2), 256, 0, stream>>>(
            cin[s], cout_[s], rin[s], rout[s], PC, PR,
            cls_tb + s * 256, reg_tb + s * 256, nullptr, 16, TAB);
    }

    // 3) cls output conv (act in D)
    pack_w<<<(72 * 52 * 64 + 255) / 256, 256, 0, stream>>>(cls_ow, PC, 819, 52);
    conv_lds<1><<<dim3(NT, 7, 1), 256, 0, stream>>>(
        D, nullptr, nullptr, nullptr, PC, nullptr, cls_ob, nullptr, out, 52, TAB);

    // 4) reg output conv (act in A) -> RAW (in B)
    pack_w<<<(72 * 3 * 64 + 255) / 256, 256, 0, stream>>>(reg_ow, PR, 36, 3);
    conv_lds<2><<<dim3(NT, 1, 1), 256, 0, stream>>>(
        A, nullptr, nullptr, nullptr, PR, nullptr, reg_ob, nullptr, RAW, 3, TAB);

    // 5) decode boxes
    decode_boxes<<<(13343 * 9 + 255) / 256, 256, 0, stream>>>(RAW, out, TAB);
}

// Round 5
// 352.775 us; speedup vs baseline: 1.4966x; 1.4966x over previous
//
#include <hip/hip_runtime.h>
#include <math.h>

typedef unsigned short u16;
typedef __attribute__((ext_vector_type(8))) short s8v;   // 8 x bf16 (4 VGPRs)
typedef __attribute__((ext_vector_type(4))) float f4v;   // MFMA accumulator

#define NUM_CLASSES 91
#define NUM_ANCHORS 9
#define NT2 247            // total 16x4 spatial tiles across 5 levels
#define TW_STRIDE (256*256*9)

struct Tab {
    int tstart[5];  // first tile index per level
    int tw[5];      // tiles along W
    int H[5], W[5], GP0[5];
};

__device__ __forceinline__ u16 f2bf(float f) {
    unsigned u = __float_as_uint(f);
    u += 0x7fffu + ((u >> 16) & 1u);
    return (u16)(u >> 16);
}

// ---------------------------------------------------------------------------
// fp32 NCHW -> bf16 [pixel][256] (channel-last), per level
// ---------------------------------------------------------------------------
__global__ __launch_bounds__(256) void conv2bf(const float* __restrict__ x,
                                               u16* __restrict__ out,
                                               int HW, int gp0)
{
    int p = blockIdx.x * 64 + (threadIdx.x & 63);
    int cg = threadIdx.x >> 6;              // 0..3
    if (p >= HW) return;
    #pragma unroll
    for (int pass = 0; pass < 8; ++pass) {
        int c0 = pass * 32 + cg * 8;
        s8v v8;
        #pragma unroll
        for (int j = 0; j < 8; ++j)
            v8[j] = (short)f2bf(x[(c0 + j) * HW + p]);
        *(s8v*)(out + (((gp0 + p) << 8) + c0)) = v8;
    }
}

// ---------------------------------------------------------------------------
// Pack conv weights [C_out][256][3][3] fp32 -> bf16 MFMA B-fragment order
// dst[((chunk*nco16 + co16)*64 + lane)*8 + j], chunk = tap*8 + cib
// ---------------------------------------------------------------------------
__global__ __launch_bounds__(256) void pack_w(const float* __restrict__ w,
                                              u16* __restrict__ dst,
                                              int c_out_real, int nco16)
{
    int idx = blockIdx.x * 256 + threadIdx.x;
    int total = 72 * nco16 * 64;
    if (idx >= total) return;
    int lane = idx & 63;
    int t2 = idx >> 6;
    int co16 = t2 % nco16;
    int chunk = t2 / nco16;
    int tap = chunk >> 3, cib = chunk & 7;
    int co = co16 * 16 + (lane & 15);
    int ci0 = cib * 32 + ((lane >> 4) << 3);
    s8v v8;
    #pragma unroll
    for (int j = 0; j < 8; ++j) {
        float v = (co < c_out_real) ? w[((co << 8) + ci0 + j) * 9 + tap] : 0.f;
        v8[j] = (short)f2bf(v);
    }
    *(s8v*)(dst + (size_t)idx * 8) = v8;
}

// ---------------------------------------------------------------------------
// LDS-staged implicit-GEMM conv. Block: 256 thr = 4 waves, each wave owns a
// 32-co slice of a 64px x 128co output tile. Spatial tile 16w x 4h, halo
// 18x6. LDS layout [kgroup(4)][halo px(108)][8 u16] -> conflict-free b128.
// Grid: (co-group fastest, tile, head) for L2/L3 act locality.
// MODE: 0 = tower (relu, bf16 ch-last), 1 = cls out (sigmoid+scatter),
//       2 = reg out (raw fp32 [pixel][48])
// ---------------------------------------------------------------------------
#define DO_TAPS(T0, T1)                                                       \
    _Pragma("unroll")                                                         \
    for (int tap = (T0); tap < (T1); ++tap) {                                 \
        s8v b[2];                                                             \
        _Pragma("unroll")                                                     \
        for (int n = 0; n < 2; ++n)                                           \
            b[n] = *(const s8v*)(bb +                                         \
                (((size_t)((tap * 8 + cib) * nco16 + c16n[n])) << 9));        \
        const int tofs = ((tap / 3 - 1) * 18 + (tap % 3 - 1)) * 8;            \
        s8v a[4];                                                             \
        _Pragma("unroll")                                                     \
        for (int s = 0; s < 4; ++s)                                           \
            a[s] = *(const s8v*)(&L[rowbase[s] + tofs]);                      \
        _Pragma("unroll")                                                     \
        for (int s = 0; s < 4; ++s)                                           \
            _Pragma("unroll")                                                 \
            for (int n = 0; n < 2; ++n)                                       \
                acc[s][n] = __builtin_amdgcn_mfma_f32_16x16x32_bf16(          \
                    a[s], b[n], acc[s][n], 0, 0, 0);                          \
    }

template<int MODE>
__global__ __launch_bounds__(256, 4) void conv_lds(
    const u16* __restrict__ actC, u16* __restrict__ outC,
    const u16* __restrict__ actR, u16* __restrict__ outR,
    const u16* __restrict__ wC, const u16* __restrict__ wR,
    const float* __restrict__ bC, const float* __restrict__ bR,
    float* __restrict__ fout, int nco16, Tab tab)
{
    __shared__ u16 lds[2][4 * 864];   // 2 x 6.9 KB: [kg][108 px][8 u16]

    const int by = blockIdx.y;
    int lvl = 0;
    if (by >= tab.tstart[1]) lvl = 1;
    if (by >= tab.tstart[2]) lvl = 2;
    if (by >= tab.tstart[3]) lvl = 3;
    if (by >= tab.tstart[4]) lvl = 4;
    const int H = tab.H[lvl], W = tab.W[lvl], gp0 = tab.GP0[lvl];
    const int t = by - tab.tstart[lvl];
    const int tw = tab.tw[lvl];
    const int w0 = (t % tw) * 16;
    const int h0 = (t / tw) * 4;

    const int head = (MODE == 0) ? blockIdx.z : 0;
    const u16* act = head ? actR : actC;
    const u16* wpk = head ? wR : wC;
    const float* bias = head ? bR : bC;

    const int tid = threadIdx.x;
    const int lane = tid & 63, wv = tid >> 6;
    const int co16w = blockIdx.x * 8 + wv * 2;    // this wave's first co16
    const int kg = lane >> 4;                     // ci sub-group 0..3

    // staging jobs: 432 x 16B lane-loads (halo 108 px x 4 parts), <=2/thread
    int sofs[2], slds[2];
    bool svalid[2], slive[2];
    #pragma unroll
    for (int i = 0; i < 2; ++i) {
        int k = tid + i * 256;
        slive[i] = k < 432;
        int kk = slive[i] ? k : 0;
        int px = kk >> 2, part = kk & 3;
        int hh = px / 18, ww = px % 18;
        int gh = h0 + hh - 1, gw = w0 + ww - 1;
        svalid[i] = ((unsigned)gh < (unsigned)H) && ((unsigned)gw < (unsigned)W);
        sofs[i] = ((gp0 + gh * W + gw) << 8) + part * 8;
        slds[i] = part * 864 + px * 8;
    }

    // per-wave constants
    int c16n[2];
    #pragma unroll
    for (int n = 0; n < 2; ++n) {
        int c = co16w + n;
        c16n[n] = (c >= nco16) ? nco16 - 1 : c;
    }
    const u16* bb = wpk + (lane << 3);
    int rowbase[4];
    #pragma unroll
    for (int s = 0; s < 4; ++s)
        rowbase[s] = kg * 864 + ((s + 1) * 18 + (lane & 15) + 1) * 8;

    f4v acc[4][2];
    #pragma unroll
    for (int s = 0; s < 4; ++s)
        #pragma unroll
        for (int n = 0; n < 2; ++n)
            acc[s][n] = (f4v){0.f, 0.f, 0.f, 0.f};

    s8v pre[2];     // in-flight stage loads
    s8v b0[2];      // tap-0 B prefetch

    auto ISSUE_S = [&](int cc) {
        #pragma unroll
        for (int i = 0; i < 2; ++i) {
            s8v v = {};
            if (slive[i] && svalid[i])
                v = *(const s8v*)(act + sofs[i] + cc * 32);
            pre[i] = v;
        }
    };
    auto ISSUE_B0 = [&](int cc) {
        #pragma unroll
        for (int n = 0; n < 2; ++n)
            b0[n] = *(const s8v*)(bb + (((size_t)(cc * nco16 + c16n[n])) << 9));
    };

    ISSUE_S(0);
    ISSUE_B0(0);
    int cur = 0;
    for (int cib = 0; cib < 8; ++cib) {
        #pragma unroll
        for (int i = 0; i < 2; ++i)
            if (slive[i]) *(s8v*)(&lds[cur][slds[i]]) = pre[i];
        __syncthreads();
        const u16* L = lds[cur];

        // tap 0 (B prefetched across the barrier)
        {
            s8v a[4];
            #pragma unroll
            for (int s = 0; s < 4; ++s)
                a[s] = *(const s8v*)(&L[rowbase[s] - 19 * 8]);
            #pragma unroll
            for (int s = 0; s < 4; ++s)
                #pragma unroll
                for (int n = 0; n < 2; ++n)
                    acc[s][n] = __builtin_amdgcn_mfma_f32_16x16x32_bf16(
                        a[s], b0[n], acc[s][n], 0, 0, 0);
        }
        DO_TAPS(1, 3)
        if (cib < 7) ISSUE_S(cib + 1);      // stage t+1 hides under taps 3..8
        DO_TAPS(3, 8)
        if (cib < 7) ISSUE_B0(cib + 1);     // next tap-0 B crosses the barrier
        DO_TAPS(8, 9)
        cur ^= 1;
        __syncthreads();
    }

    // ---- epilogue: D col = lane&15 -> co; D row = (lane>>4)*4+j -> px col ----
    u16* outw = head ? outR : outC;
    #pragma unroll
    for (int n = 0; n < 2; ++n) {
        const int co = (co16w + n) * 16 + (lane & 15);   // real, unclamped
        #pragma unroll
        for (int s = 0; s < 4; ++s) {
            const int h = h0 + s;
            #pragma unroll
            for (int j = 0; j < 4; ++j) {
                const int w = w0 + ((lane >> 4) << 2) + j;
                if (h < H && w < W) {
                    const int p = h * W + w;
                    if (MODE == 0) {
                        float v = acc[s][n][j] + bias[co];
                        outw[((gp0 + p) << 8) + co] = f2bf(fmaxf(v, 0.f));
                    } else if (MODE == 1) {
                        if (co < NUM_ANCHORS * NUM_CLASSES) {
                            float v = acc[s][n][j] + bias[co];
                            int a = co / NUM_CLASSES;
                            int k = co - a * NUM_CLASSES;
                            float sg = 1.f / (1.f + __expf(-v));
                            fout[((size_t)(gp0 + p) * 9 + a) * 95 + k] = sg;
                        }
                    } else {
                        if (co < 36)
                            fout[(gp0 + p) * 48 + co] = acc[s][n][j] + bias[co];
                    }
                }
            }
        }
    }
}

// ---------------------------------------------------------------------------
// box decode from raw [pixel][48]
// ---------------------------------------------------------------------------
__global__ __launch_bounds__(256) void decode_boxes(
    const float* __restrict__ raw, float* __restrict__ out, Tab tab)
{
    int idx = blockIdx.x * 256 + threadIdx.x;
    if (idx >= 13343 * 9) return;
    int gp = idx / 9, a = idx % 9;
    int lvl = 0;
    if (gp >= tab.GP0[1]) lvl = 1;
    if (gp >= tab.GP0[2]) lvl = 2;
    if (gp >= tab.GP0[3]) lvl = 3;
    if (gp >= tab.GP0[4]) lvl = 4;
    int p = gp - tab.GP0[lvl];
    int W = tab.W[lvl];
    int h = p / W, wc = p % W;
    float stride = (float)(8 << lvl);
    float base = (float)(32 << lvl);

    float dx = raw[gp * 48 + a * 4 + 0];
    float dy = raw[gp * 48 + a * 4 + 1];
    float dw = raw[gp * 48 + a * 4 + 2];
    float dh = raw[gp * 48 + a * 4 + 3];

    const float scales[3] = {1.f, 1.2599210498948732f, 1.5874010519681994f};
    const float hr[3] = {0.70710678118654752f, 1.f, 1.41421356237309505f};
    int ri = a / 3, si = a % 3;
    float sz = base * scales[si];
    float ah = hr[ri] * sz;
    float aw = sz / hr[ri];
    float acx = (float)wc * stride;
    float acy = (float)h * stride;

    const float CLAMP = 4.135166556742356f;
    dw = fminf(dw, CLAMP);
    dh = fminf(dh, CLAMP);
    float pcx = dx * aw + acx;
    float pcy = dy * ah + acy;
    float pw = expf(dw) * aw;
    float ph = expf(dh) * ah;

    float* o = out + ((size_t)gp * 9 + a) * 95 + 91;
    o[0] = pcx - 0.5f * pw;
    o[1] = pcy - 0.5f * ph;
    o[2] = pcx + 0.5f * pw;
    o[3] = pcy + 0.5f * ph;
}

// ---------------------------------------------------------------------------
extern "C" void kernel_launch(void* const* d_in, const int* in_sizes, int n_in,
                              void* d_out, int out_size, void* d_ws, size_t ws_size,
                              hipStream_t stream)
{
    const float* feats[5];
    for (int i = 0; i < 5; ++i) feats[i] = (const float*)d_in[i];
    const float* cls_tw = (const float*)d_in[5];
    const float* cls_tb = (const float*)d_in[6];
    const float* cls_ow = (const float*)d_in[7];
    const float* cls_ob = (const float*)d_in[8];
    const float* reg_tw = (const float*)d_in[9];
    const float* reg_tb = (const float*)d_in[10];
    const float* reg_ow = (const float*)d_in[11];
    const float* reg_ob = (const float*)d_in[12];
    float* out = (float*)d_out;

    static const Tab TAB = {
        {0, 175, 227, 241, 245},
        {7, 4, 2, 1, 1},
        {100, 50, 25, 13, 7},
        {100, 50, 25, 13, 7},
        {0, 10000, 12500, 13125, 13294}
    };
    static const int HWs[5] = {10000, 2500, 625, 169, 49};

    char* wsb = (char*)d_ws;
    const size_t AS = 6832128;                 // act buffer stride (bytes)
    u16* A = (u16*)(wsb + 0 * AS);
    u16* B = (u16*)(wsb + 1 * AS);
    u16* C = (u16*)(wsb + 2 * AS);
    u16* D = (u16*)(wsb + 3 * AS);
    float* RAW = (float*)B;                    // reg raw out, reuses B

    const u16* cin[4]   = {A, B, D, B};
    u16*       cout_[4] = {B, D, B, D};
    const u16* rin[4]   = {A, C, A, C};
    u16*       rout[4]  = {C, A, C, A};

    const size_t PTSZ = 1179648;               // one packed tower layer (bytes)
    const bool big = ws_size >= (4 * AS + 8 * PTSZ + 3833856 + 221184);

    // 1) feats -> bf16 channel-last into A
    for (int l = 0; l < 5; ++l)
        conv2bf<<<(HWs[l] + 63) / 64, 256, 0, stream>>>(feats[l], A, HWs[l], TAB.GP0[l]);

    if (big) {
        // pack everything up front (no inter-stage pack bubbles)
        u16* PT = (u16*)(wsb + 4 * AS);
        u16* PC = (u16*)(wsb + 4 * AS + 8 * PTSZ);
        u16* PR = (u16*)(wsb + 4 * AS + 8 * PTSZ + 3833856);
        for (int s = 0; s < 4; ++s) {
            pack_w<<<(72 * 16 * 64 + 255) / 256, 256, 0, stream>>>(
                cls_tw + s * TW_STRIDE, PT + (size_t)s * (PTSZ / 2), 256, 16);
            pack_w<<<(72 * 16 * 64 + 255) / 256, 256, 0, stream>>>(
                reg_tw + s * TW_STRIDE, PT + (size_t)(4 + s) * (PTSZ / 2), 256, 16);
        }
        pack_w<<<(72 * 52 * 64 + 255) / 256, 256, 0, stream>>>(cls_ow, PC, 819, 52);
        pack_w<<<(72 * 3 * 64 + 255) / 256, 256, 0, stream>>>(reg_ow, PR, 36, 3);

        for (int s = 0; s < 4; ++s)
            conv_lds<0><<<dim3(2, NT2, 2), 256, 0, stream>>>(
                cin[s], cout_[s], rin[s], rout[s],
                PT + (size_t)s * (PTSZ / 2), PT + (size_t)(4 + s) * (PTSZ / 2),
                cls_tb + s * 256, reg_tb + s * 256, nullptr, 16, TAB);

        conv_lds<1><<<dim3(7, NT2, 1), 256, 0, stream>>>(
            D, nullptr, nullptr, nullptr, PC, nullptr, cls_ob, nullptr, out, 52, TAB);
        conv_lds<2><<<dim3(1, NT2, 1), 256, 0, stream>>>(
            A, nullptr, nullptr, nullptr, PR, nullptr, reg_ob, nullptr, RAW, 3, TAB);
    } else {
        // fallback: per-stage packing into shared scratch
        u16* PC = (u16*)(wsb + 4 * AS);
        u16* PR = (u16*)(wsb + 4 * AS + 3833856);
        for (int s = 0; s < 4; ++s) {
            pack_w<<<(72 * 16 * 64 + 255) / 256, 256, 0, stream>>>(cls_tw + s * TW_STRIDE, PC, 256, 16);
            pack_w<<<(72 * 16 * 64 + 255) / 256, 256, 0, stream>>>(reg_tw + s * TW_STRIDE, PR, 256, 16);
            conv_lds<0><<<dim3(2, NT2, 2), 256, 0, stream>>>(
                cin[s], cout_[s], rin[s], rout[s], PC, PR,
                cls_tb + s * 256, reg_tb + s * 256, nullptr, 16, TAB);
        }
        pack_w<<<(72 * 52 * 64 + 255) / 256, 256, 0, stream>>>(cls_ow, PC, 819, 52);
        conv_lds<1><<<dim3(7, NT2, 1), 256, 0, stream>>>(
            D, nullptr, nullptr, nullptr, PC, nullptr, cls_ob, nullptr, out, 52, TAB);
        pack_w<<<(72 * 3 * 64 + 255) / 256, 256, 0, stream>>>(reg_ow, PR, 36, 3);
        conv_lds<2><<<dim3(1, NT2, 1), 256, 0, stream>>>(
            A, nullptr, nullptr, nullptr, PR, nullptr, reg_ob, nullptr, RAW, 3, TAB);
    }

    // 5) decode boxes
    decode_boxes<<<(13343 * 9 + 255) / 256, 256, 0, stream>>>(RAW, out, TAB);
}

// Round 6
// 351.763 us; speedup vs baseline: 1.5009x; 1.0029x over previous
//
#include <hip/hip_runtime.h>
#include <math.h>

typedef unsigned short u16;
typedef __attribute__((ext_vector_type(8))) short s8v;   // 8 x bf16 (4 VGPRs)
typedef __attribute__((ext_vector_type(4))) float f4v;   // MFMA accumulator

#define NUM_CLASSES 91
#define NUM_ANCHORS 9
#define NT2 247            // total 16x4 spatial tiles across 5 levels
#define TW_STRIDE (256*256*9)

struct Tab {
    int tstart[5];  // first tile index per level
    int tw[5];      // tiles along W
    int H[5], W[5], GP0[5];
};

__device__ __forceinline__ u16 f2bf(float f) {
    unsigned u = __float_as_uint(f);
    u += 0x7fffu + ((u >> 16) & 1u);
    return (u16)(u >> 16);
}

// ---------------------------------------------------------------------------
// fp32 NCHW -> bf16 [pixel][256] (channel-last), all levels in one launch
// ---------------------------------------------------------------------------
__global__ __launch_bounds__(256) void conv2bf_all(
    const float* __restrict__ f0, const float* __restrict__ f1,
    const float* __restrict__ f2, const float* __restrict__ f3,
    const float* __restrict__ f4, u16* __restrict__ out, Tab tab)
{
    int gp = blockIdx.x * 64 + (threadIdx.x & 63);
    int cg = threadIdx.x >> 6;              // 0..3
    if (gp >= 13343) return;
    int lvl = 0;
    if (gp >= tab.GP0[1]) lvl = 1;
    if (gp >= tab.GP0[2]) lvl = 2;
    if (gp >= tab.GP0[3]) lvl = 3;
    if (gp >= tab.GP0[4]) lvl = 4;
    const float* x = lvl == 0 ? f0 : lvl == 1 ? f1 : lvl == 2 ? f2 : lvl == 3 ? f3 : f4;
    int p = gp - tab.GP0[lvl];
    int HW = tab.H[lvl] * tab.W[lvl];
    #pragma unroll
    for (int pass = 0; pass < 8; ++pass) {
        int c0 = pass * 32 + cg * 8;
        s8v v8;
        #pragma unroll
        for (int j = 0; j < 8; ++j)
            v8[j] = (short)f2bf(x[(c0 + j) * HW + p]);
        *(s8v*)(out + (((size_t)gp << 8) + c0)) = v8;
    }
}

// ---------------------------------------------------------------------------
// Pack conv weights [C_out][256][3][3] fp32 -> bf16 MFMA B-fragment order
// dst[((chunk*nco16 + co16)*64 + lane)*8 + j], chunk = tap*8 + cib
// ---------------------------------------------------------------------------
__global__ __launch_bounds__(256) void pack_w(const float* __restrict__ w,
                                              u16* __restrict__ dst,
                                              int c_out_real, int nco16)
{
    int idx = blockIdx.x * 256 + threadIdx.x;
    int total = 72 * nco16 * 64;
    if (idx >= total) return;
    int lane = idx & 63;
    int t2 = idx >> 6;
    int co16 = t2 % nco16;
    int chunk = t2 / nco16;
    int tap = chunk >> 3, cib = chunk & 7;
    int co = co16 * 16 + (lane & 15);
    int ci0 = cib * 32 + ((lane >> 4) << 3);
    s8v v8;
    #pragma unroll
    for (int j = 0; j < 8; ++j) {
        float v = (co < c_out_real) ? w[((co << 8) + ci0 + j) * 9 + tap] : 0.f;
        v8[j] = (short)f2bf(v);
    }
    *(s8v*)(dst + (size_t)idx * 8) = v8;
}

// ---------------------------------------------------------------------------
// LDS-staged implicit-GEMM conv. Block: 256 thr = 4 waves; wave owns
// 64px x (ACCN*16)co. Spatial tile 16w x 4h, halo 18x6 staged per 32-ci
// chunk in LDS [part(4)][108 px][8 u16]. NCO16 = total co16 (templated so
// all B offsets are compile-time). Grid: (co-grp, tile, head).
// MODE: 0 = tower (relu, bf16 ch-last), 1 = cls out (sigmoid+scatter),
//       2 = reg out (raw fp32 [pixel][48])
// ---------------------------------------------------------------------------
template<int MODE, int NCO16, int ACCN>
__global__ __launch_bounds__(256, (MODE == 0 ? 2 : 4)) void conv_lds(
    const u16* __restrict__ actC, u16* __restrict__ outC,
    const u16* __restrict__ actR, u16* __restrict__ outR,
    const u16* __restrict__ wC, const u16* __restrict__ wR,
    const float* __restrict__ bC, const float* __restrict__ bR,
    float* __restrict__ fout, Tab tab)
{
    __shared__ u16 lds[4 * 864];   // 6.9 KB: [part][108 px][8 u16]

    const int by = blockIdx.y;
    int lvl = 0;
    if (by >= tab.tstart[1]) lvl = 1;
    if (by >= tab.tstart[2]) lvl = 2;
    if (by >= tab.tstart[3]) lvl = 3;
    if (by >= tab.tstart[4]) lvl = 4;
    const int H = tab.H[lvl], W = tab.W[lvl], gp0 = tab.GP0[lvl];
    const int t = by - tab.tstart[lvl];
    const int tw = tab.tw[lvl];
    const int w0 = (t % tw) * 16;
    const int h0 = (t / tw) * 4;

    const int head = (MODE == 0) ? blockIdx.z : 0;
    const u16* act = head ? actR : actC;
    const u16* wpk = head ? wR : wC;
    const float* bias = head ? bR : bC;

    const int tid = threadIdx.x;
    const int lane = tid & 63, wv = tid >> 6;
    const int co16w = blockIdx.x * (4 * ACCN) + wv * ACCN;  // wave's first co16
    const int kg = lane >> 4;                               // ci sub-group 0..3

    // staging jobs: 432 x 16B lane-loads (halo 108 px x 4 parts), <=2/thread
    int sofs[2], slds[2];
    bool svalid[2], slive[2];
    #pragma unroll
    for (int i = 0; i < 2; ++i) {
        int k = tid + i * 256;
        slive[i] = k < 432;
        int kk = slive[i] ? k : 0;
        int px = kk >> 2, part = kk & 3;
        int hh = px / 18, ww = px % 18;
        int gh = h0 + hh - 1, gw = w0 + ww - 1;
        svalid[i] = ((unsigned)gh < (unsigned)H) && ((unsigned)gw < (unsigned)W);
        sofs[i] = ((gp0 + gh * W + gw) << 8) + part * 8;
        slds[i] = part * 864 + px * 8;
    }

    // per-wave B base pointers (clamped co16), compile-time stride offsets
    const u16* bbn[ACCN];
    #pragma unroll
    for (int n = 0; n < ACCN; ++n) {
        int c = co16w + n;
        if (c >= NCO16) c = NCO16 - 1;
        bbn[n] = wpk + (size_t)c * 1024 + (lane << 3);
    }
    int rowbase[4];
    #pragma unroll
    for (int s = 0; s < 4; ++s)
        rowbase[s] = kg * 864 + ((s + 1) * 18 + (lane & 15) + 1) * 8;

    f4v acc[4][ACCN];
    #pragma unroll
    for (int s = 0; s < 4; ++s)
        #pragma unroll
        for (int n = 0; n < ACCN; ++n)
            acc[s][n] = (f4v){0.f, 0.f, 0.f, 0.f};

    for (int cib = 0; cib < 8; ++cib) {
        if (cib) __syncthreads();     // protect prev chunk's reads
        #pragma unroll
        for (int i = 0; i < 2; ++i) {
            if (slive[i]) {
                s8v v = {};
                if (svalid[i]) v = *(const s8v*)(act + sofs[i] + cib * 32);
                *(s8v*)(&lds[slds[i]]) = v;
            }
        }
        __syncthreads();

        #pragma unroll
        for (int tap = 0; tap < 9; ++tap) {
            s8v b[ACCN];
            #pragma unroll
            for (int n = 0; n < ACCN; ++n)
                b[n] = *(const s8v*)(bbn[n] +
                    (size_t)(tap * 8 + cib) * (NCO16 * 1024));
            const int tofs = ((tap / 3 - 1) * 18 + (tap % 3 - 1)) * 8;
            s8v a[4];
            #pragma unroll
            for (int s = 0; s < 4; ++s)
                a[s] = *(const s8v*)(&lds[rowbase[s] + tofs]);
            #pragma unroll
            for (int s = 0; s < 4; ++s)
                #pragma unroll
                for (int n = 0; n < ACCN; ++n)
                    acc[s][n] = __builtin_amdgcn_mfma_f32_16x16x32_bf16(
                        a[s], b[n], acc[s][n], 0, 0, 0);
        }
    }

    // ---- epilogue: D col = lane&15 -> co; D row = (lane>>4)*4+j -> px ----
    u16* outw = head ? outR : outC;
    #pragma unroll
    for (int n = 0; n < ACCN; ++n) {
        const int co = (co16w + n) * 16 + (lane & 15);   // real, unclamped
        #pragma unroll
        for (int s = 0; s < 4; ++s) {
            const int h = h0 + s;
            #pragma unroll
            for (int j = 0; j < 4; ++j) {
                const int w = w0 + ((lane >> 4) << 2) + j;
                if (h < H && w < W) {
                    const int p = h * W + w;
                    if (MODE == 0) {
                        float v = acc[s][n][j] + bias[co];
                        outw[((size_t)(gp0 + p) << 8) + co] = f2bf(fmaxf(v, 0.f));
                    } else if (MODE == 1) {
                        if (co < NUM_ANCHORS * NUM_CLASSES) {
                            float v = acc[s][n][j] + bias[co];
                            int a = co / NUM_CLASSES;
                            int k = co - a * NUM_CLASSES;
                            float sg = 1.f / (1.f + __expf(-v));
                            fout[((size_t)(gp0 + p) * 9 + a) * 95 + k] = sg;
                        }
                    } else {
                        if (co < 36)
                            fout[(gp0 + p) * 48 + co] = acc[s][n][j] + bias[co];
                    }
                }
            }
        }
    }
}

// ---------------------------------------------------------------------------
// box decode from raw [pixel][48]
// ---------------------------------------------------------------------------
__global__ __launch_bounds__(256) void decode_boxes(
    const float* __restrict__ raw, float* __restrict__ out, Tab tab)
{
    int idx = blockIdx.x * 256 + threadIdx.x;
    if (idx >= 13343 * 9) return;
    int gp = idx / 9, a = idx % 9;
    int lvl = 0;
    if (gp >= tab.GP0[1]) lvl = 1;
    if (gp >= tab.GP0[2]) lvl = 2;
    if (gp >= tab.GP0[3]) lvl = 3;
    if (gp >= tab.GP0[4]) lvl = 4;
    int p = gp - tab.GP0[lvl];
    int W = tab.W[lvl];
    int h = p / W, wc = p % W;
    float stride = (float)(8 << lvl);
    float base = (float)(32 << lvl);

    float dx = raw[gp * 48 + a * 4 + 0];
    float dy = raw[gp * 48 + a * 4 + 1];
    float dw = raw[gp * 48 + a * 4 + 2];
    float dh = raw[gp * 48 + a * 4 + 3];

    const float scales[3] = {1.f, 1.2599210498948732f, 1.5874010519681994f};
    const float hr[3] = {0.70710678118654752f, 1.f, 1.41421356237309505f};
    int ri = a / 3, si = a % 3;
    float sz = base * scales[si];
    float ah = hr[ri] * sz;
    float aw = sz / hr[ri];
    float acx = (float)wc * stride;
    float acy = (float)h * stride;

    const float CLAMP = 4.135166556742356f;
    dw = fminf(dw, CLAMP);
    dh = fminf(dh, CLAMP);
    float pcx = dx * aw + acx;
    float pcy = dy * ah + acy;
    float pw = expf(dw) * aw;
    float ph = expf(dh) * ah;

    float* o = out + ((size_t)gp * 9 + a) * 95 + 91;
    o[0] = pcx - 0.5f * pw;
    o[1] = pcy - 0.5f * ph;
    o[2] = pcx + 0.5f * pw;
    o[3] = pcy + 0.5f * ph;
}

// ---------------------------------------------------------------------------
extern "C" void kernel_launch(void* const* d_in, const int* in_sizes, int n_in,
                              void* d_out, int out_size, void* d_ws, size_t ws_size,
                              hipStream_t stream)
{
    const float* f0 = (const float*)d_in[0];
    const float* f1 = (const float*)d_in[1];
    const float* f2 = (const float*)d_in[2];
    const float* f3 = (const float*)d_in[3];
    const float* f4 = (const float*)d_in[4];
    const float* cls_tw = (const float*)d_in[5];
    const float* cls_tb = (const float*)d_in[6];
    const float* cls_ow = (const float*)d_in[7];
    const float* cls_ob = (const float*)d_in[8];
    const float* reg_tw = (const float*)d_in[9];
    const float* reg_tb = (const float*)d_in[10];
    const float* reg_ow = (const float*)d_in[11];
    const float* reg_ob = (const float*)d_in[12];
    float* out = (float*)d_out;

    static const Tab TAB = {
        {0, 175, 227, 241, 245},
        {7, 4, 2, 1, 1},
        {100, 50, 25, 13, 7},
        {100, 50, 25, 13, 7},
        {0, 10000, 12500, 13125, 13294}
    };

    char* wsb = (char*)d_ws;
    const size_t AS = 6832128;                 // act buffer stride (bytes)
    u16* A = (u16*)(wsb + 0 * AS);
    u16* B = (u16*)(wsb + 1 * AS);
    u16* C = (u16*)(wsb + 2 * AS);
    u16* D = (u16*)(wsb + 3 * AS);
    float* RAW = (float*)B;                    // reg raw out, reuses B

    const u16* cin[4]   = {A, B, D, B};
    u16*       cout_[4] = {B, D, B, D};
    const u16* rin[4]   = {A, C, A, C};
    u16*       rout[4]  = {C, A, C, A};

    const size_t PTSZ = 1179648;               // one packed tower layer (bytes)
    const bool big = ws_size >= (4 * AS + 8 * PTSZ + 3833856 + 221184);

    // 1) feats -> bf16 channel-last into A (one launch)
    conv2bf_all<<<(13343 + 63) / 64, 256, 0, stream>>>(f0, f1, f2, f3, f4, A, TAB);

    if (big) {
        // pack everything up front (no inter-stage pack bubbles)
        u16* PT = (u16*)(wsb + 4 * AS);
        u16* PC = (u16*)(wsb + 4 * AS + 8 * PTSZ);
        u16* PR = (u16*)(wsb + 4 * AS + 8 * PTSZ + 3833856);
        for (int s = 0; s < 4; ++s) {
            pack_w<<<(72 * 16 * 64 + 255) / 256, 256, 0, stream>>>(
                cls_tw + s * TW_STRIDE, PT + (size_t)s * (PTSZ / 2), 256, 16);
            pack_w<<<(72 * 16 * 64 + 255) / 256, 256, 0, stream>>>(
                reg_tw + s * TW_STRIDE, PT + (size_t)(4 + s) * (PTSZ / 2), 256, 16);
        }
        pack_w<<<(72 * 52 * 64 + 255) / 256, 256, 0, stream>>>(cls_ow, PC, 819, 52);
        pack_w<<<(72 * 3 * 64 + 255) / 256, 256, 0, stream>>>(reg_ow, PR, 36, 3);

        for (int s = 0; s < 4; ++s)
            conv_lds<0, 16, 4><<<dim3(1, NT2, 2), 256, 0, stream>>>(
                cin[s], cout_[s], rin[s], rout[s],
                PT + (size_t)s * (PTSZ / 2), PT + (size_t)(4 + s) * (PTSZ / 2),
                cls_tb + s * 256, reg_tb + s * 256, nullptr, TAB);

        conv_lds<1, 52, 2><<<dim3(7, NT2, 1), 256, 0, stream>>>(
            D, nullptr, nullptr, nullptr, PC, nullptr, cls_ob, nullptr, out, TAB);
        conv_lds<2, 3, 1><<<dim3(1, NT2, 1), 256, 0, stream>>>(
            A, nullptr, nullptr, nullptr, PR, nullptr, reg_ob, nullptr, RAW, TAB);
    } else {
        // fallback: per-stage packing into shared scratch
        u16* PC = (u16*)(wsb + 4 * AS);
        u16* PR = (u16*)(wsb + 4 * AS + 3833856);
        for (int s = 0; s < 4; ++s) {
            pack_w<<<(72 * 16 * 64 + 255) / 256, 256, 0, stream>>>(cls_tw + s * TW_STRIDE, PC, 256, 16);
            pack_w<<<(72 * 16 * 64 + 255) / 256, 256, 0, stream>>>(reg_tw + s * TW_STRIDE, PR, 256, 16);
            conv_lds<0, 16, 4><<<dim3(1, NT2, 2), 256, 0, stream>>>(
                cin[s], cout_[s], rin[s], rout[s], PC, PR,
                cls_tb + s * 256, reg_tb + s * 256, nullptr, TAB);
        }
        pack_w<<<(72 * 52 * 64 + 255) / 256, 256, 0, stream>>>(cls_ow, PC, 819, 52);
        conv_lds<1, 52, 2><<<dim3(7, NT2, 1), 256, 0, stream>>>(
            D, nullptr, nullptr, nullptr, PC, nullptr, cls_ob, nullptr, out, TAB);
        pack_w<<<(72 * 3 * 64 + 255) / 256, 256, 0, stream>>>(reg_ow, PR, 36, 3);
        conv_lds<2, 3, 1><<<dim3(1, NT2, 1), 256, 0, stream>>>(
            A, nullptr, nullptr, nullptr, PR, nullptr, reg_ob, nullptr, RAW, TAB);
    }

    // 5) decode boxes
    decode_boxes<<<(13343 * 9 + 255) / 256, 256, 0, stream>>>(RAW, out, TAB);
}